// Round 1
// baseline (73.950 us; speedup 1.0000x reference)
//
#include <hip/hip_runtime.h>
#include <math.h>

#define MARGIN 1.0f
#define TI 256   // i's per block (one per thread)
#define TJ 512   // j's per LDS tile

// ---------------- Kernel A: per-row distance ----------------
__global__ __launch_bounds__(256) void dist_kernel(
    const float* __restrict__ pv,   // (B, P)
    const float* __restrict__ pt,   // (P,)
    float* __restrict__ dist,       // (B,)
    int B, int P)
{
    int i = blockIdx.x * blockDim.x + threadIdx.x;
    if (i >= B) return;
    const float* row = pv + (size_t)i * P;
    float s = 0.f;
    // P is small (16); pt[] is wave-uniform -> scalar loads
    for (int p = 0; p < P; ++p) {
        float d = row[p] - pt[p];
        s = fmaf(d, d, s);
    }
    dist[i] = sqrtf(s);
}

// ---------------- Kernel B: all-pairs masked loss ----------------
__global__ __launch_bounds__(256) void pair_kernel(
    const float* __restrict__ e,     // (B,)  energies flat
    const float* __restrict__ dist,  // (B,)
    float* __restrict__ psum,        // (nblk,)
    float* __restrict__ pcnt,        // (nblk,)
    int B, int nj_tiles)
{
    __shared__ float sd[TJ];
    __shared__ float se[TJ];

    int it = blockIdx.x / nj_tiles;
    int jt = blockIdx.x % nj_tiles;
    int j0 = jt * TJ;

    // stage j-tile into LDS
    for (int k = threadIdx.x; k < TJ; k += 256) {
        int j = j0 + k;
        bool ok = (j < B);
        sd[k] = ok ? dist[j] : -INFINITY;  // -inf: never satisfies di < dj
        se[k] = ok ? e[j]    : 0.f;
    }
    __syncthreads();

    int i = it * TI + (int)threadIdx.x;
    bool iok = (i < B);
    float di = iok ? dist[i] : INFINITY;   // +inf: di < dj never true
    float a  = iok ? (e[i] + MARGIN) : 0.f;

    float sum = 0.f, cnt = 0.f;
    #pragma unroll 8
    for (int k = 0; k < TJ; ++k) {
        float dj = sd[k];   // same-address broadcast: conflict-free
        float ej = se[k];
        bool m  = (di < dj);           // diagonal self-excludes (di<di false)
        float t = fmaxf(a - ej, 0.f);  // relu(e_i - e_j + margin)
        sum += m ? t   : 0.f;
        cnt += m ? 1.f : 0.f;
    }

    // block tree reduction
    __shared__ float rs[256];
    __shared__ float rc[256];
    rs[threadIdx.x] = sum;
    rc[threadIdx.x] = cnt;
    __syncthreads();
    for (int s = 128; s > 0; s >>= 1) {
        if ((int)threadIdx.x < s) {
            rs[threadIdx.x] += rs[threadIdx.x + s];
            rc[threadIdx.x] += rc[threadIdx.x + s];
        }
        __syncthreads();
    }
    if (threadIdx.x == 0) {
        psum[blockIdx.x] = rs[0];
        pcnt[blockIdx.x] = rc[0];
    }
}

// ---------------- Kernel C: final reduce + divide ----------------
__global__ __launch_bounds__(256) void finalize_kernel(
    const float* __restrict__ psum,
    const float* __restrict__ pcnt,
    float* __restrict__ out,
    int nblk)
{
    __shared__ double ss[256];
    __shared__ double sc[256];
    double s = 0.0, c = 0.0;
    for (int k = threadIdx.x; k < nblk; k += 256) {
        s += (double)psum[k];
        c += (double)pcnt[k];
    }
    ss[threadIdx.x] = s;
    sc[threadIdx.x] = c;
    __syncthreads();
    for (int st = 128; st > 0; st >>= 1) {
        if ((int)threadIdx.x < st) {
            ss[threadIdx.x] += ss[threadIdx.x + st];
            sc[threadIdx.x] += sc[threadIdx.x + st];
        }
        __syncthreads();
    }
    if (threadIdx.x == 0) {
        double cnt = sc[0] < 1.0 ? 1.0 : sc[0];
        out[0] = (float)(ss[0] / cnt);
    }
}

extern "C" void kernel_launch(void* const* d_in, const int* in_sizes, int n_in,
                              void* d_out, int out_size, void* d_ws, size_t ws_size,
                              hipStream_t stream)
{
    const float* energies = (const float*)d_in[0];  // (B,1) flat = B floats
    const float* pv       = (const float*)d_in[1];  // (B,P)
    const float* pt       = (const float*)d_in[2];  // (P,)
    int B = in_sizes[0];
    int P = in_sizes[2];

    int ni = (B + TI - 1) / TI;
    int nj = (B + TJ - 1) / TJ;
    int nblk = ni * nj;

    float* dist = (float*)d_ws;          // B floats
    float* psum = dist + B;              // nblk floats
    float* pcnt = psum + nblk;           // nblk floats

    dist_kernel<<<(B + 255) / 256, 256, 0, stream>>>(pv, pt, dist, B, P);
    pair_kernel<<<nblk, 256, 0, stream>>>(energies, dist, psum, pcnt, B, nj);
    finalize_kernel<<<1, 256, 0, stream>>>(psum, pcnt, (float*)d_out, nblk);
}